// Round 7
// baseline (900.307 us; speedup 1.0000x reference)
//
#include <hip/hip_runtime.h>
#include <stdint.h>
#include <stddef.h>

typedef float f32x16 __attribute__((ext_vector_type(16)));
typedef int i32x8 __attribute__((ext_vector_type(8)));

union Frag32 { long l[4]; i32x8 v; };  // 32 bytes = one scaled-MFMA operand/lane

// ---------------------------------------------------------------------------
// Quantized operands live in an "LDS-image" layout: 8 KB slots; slot
// s = blk*(K/32) + ksl holds rows [blk*256..+256) x k-bytes [ksl*32..+32).
// Within a 32B row, logical 8B chunk j is stored at physical chunk
// j ^ ((row>>2)&3).  GEMM stages 16 KB slices (2 slots) with a LINEAR
// contiguous copy (global_load_lds x16); fragment ds_read_b64 at
// P = h*8192 + row*32 + ((j ^ ((row>>2)&3))*8) is bank-pair-bijective:
// zero conflicts (R3-R6 verified: SQ_LDS_BANK_CONFLICT = 0).
//
// GEMM inner op: mfma_scale_f32_32x32x64_f8f6f4 with unit E8M0 scales
// (0x7F/byte -> x1.0): bit-exact fp8 matmul at the 2x MX rate.
//
// Workspace layout (bytes):
//   [0..7]    : two u32 atomic absmax slots (w_absmax_bits, x_absmax_bits)
//   [256 .. 256+M*K)            : x_q  LDS-image slots (32 MB)
//   [256+M*K .. 256+M*K+N*K)    : w_qT LDS-image slots (64 MB)
// ---------------------------------------------------------------------------

__global__ void absmax_kernel(const float4* __restrict__ x, size_t n4,
                              unsigned int* __restrict__ out) {
  size_t idx = ((size_t)blockIdx.x * blockDim.x + threadIdx.x) * 2;
  size_t stride = (size_t)gridDim.x * blockDim.x * 2;
  float m0 = 0.f, m1 = 0.f;
  for (size_t i = idx; i < n4; i += stride) {
    float4 v = x[i];
    float4 u = x[i + 1];  // n4 is even for both inputs
    m0 = fmaxf(m0, fmaxf(fmaxf(fabsf(v.x), fabsf(v.y)),
                         fmaxf(fabsf(v.z), fabsf(v.w))));
    m1 = fmaxf(m1, fmaxf(fmaxf(fabsf(u.x), fabsf(u.y)),
                         fmaxf(fabsf(u.z), fabsf(u.w))));
  }
  float m = fmaxf(m0, m1);
#pragma unroll
  for (int off = 32; off > 0; off >>= 1)
    m = fmaxf(m, __shfl_xor(m, off));
  if ((threadIdx.x & 63) == 0)
    atomicMax(out, __float_as_uint(m));  // all values >= 0: uint order == float order
}

// x [M][K] f32 -> LDS-image slots. One thread = one 16B logical chunk.
__global__ void quantize_x_kernel(const float4* __restrict__ x,
                                  uint8_t* __restrict__ xq,
                                  const unsigned int* __restrict__ amax,
                                  int K, int n_chunks) {
  const float x_scale = __uint_as_float(amax[1]) / 448.0f;
  const float inv = 1.0f / x_scale;
  const int kslots = K >> 5;
  int idx = blockIdx.x * blockDim.x + threadIdx.x;
  const int stride = gridDim.x * blockDim.x;
  for (; idx < n_chunks; idx += stride) {
    const int slot = idx >> 9;        // 512 chunks of 16B per 8KB slot
    const int p16 = idx & 511;
    const int row = p16 >> 1;
    const int kkb0 = (p16 & 1) << 4;
    const int mblk = slot / kslots;
    const int ksl = slot - mblk * kslots;
    const size_t f4 = ((size_t)(mblk * 256 + row) * K + ksl * 32 + kkb0) >> 2;
    const float4 v0 = x[f4 + 0], v1 = x[f4 + 1], v2 = x[f4 + 2], v3 = x[f4 + 3];
    uint32_t c0 = __builtin_amdgcn_cvt_pk_fp8_f32(v0.x * inv, v0.y * inv, 0, false);
    c0 = __builtin_amdgcn_cvt_pk_fp8_f32(v0.z * inv, v0.w * inv, c0, true);
    uint32_t c1 = __builtin_amdgcn_cvt_pk_fp8_f32(v1.x * inv, v1.y * inv, 0, false);
    c1 = __builtin_amdgcn_cvt_pk_fp8_f32(v1.z * inv, v1.w * inv, c1, true);
    uint32_t c2 = __builtin_amdgcn_cvt_pk_fp8_f32(v2.x * inv, v2.y * inv, 0, false);
    c2 = __builtin_amdgcn_cvt_pk_fp8_f32(v2.z * inv, v2.w * inv, c2, true);
    uint32_t c3 = __builtin_amdgcn_cvt_pk_fp8_f32(v3.x * inv, v3.y * inv, 0, false);
    c3 = __builtin_amdgcn_cvt_pk_fp8_f32(v3.z * inv, v3.w * inv, c3, true);
    const unsigned long long L0 = (unsigned long long)c0 | ((unsigned long long)c1 << 32);
    const unsigned long long L1 = (unsigned long long)c2 | ((unsigned long long)c3 << 32);
    const int Lc = row * 32 + kkb0;
    const int mask = ((row >> 2) & 3) << 3;
    const int addr0 = Lc ^ (mask & 16);
    uint8_t* p = xq + (size_t)slot * 8192;
    *(unsigned long long*)(p + addr0 + (mask & 8)) = L0;
    *(unsigned long long*)(p + addr0 + (8 ^ (mask & 8))) = L1;
  }
}

// w [K][N] f32 -> w^T LDS-image slots. 64n x 128k tile per block:
// f32 LDS tile [64][129] (pad: conflict-free b32 scatter-writes and b128
// column reads), register-side chunk permute, contiguous 32B stores.
__global__ void quantize_wT_kernel(const float* __restrict__ w,
                                   uint8_t* __restrict__ wqt,
                                   const unsigned int* __restrict__ amax,
                                   int N, int K) {
  __shared__ float tileF[64][129];
  const float w_scale = __uint_as_float(amax[0]) / 448.0f;
  const float inv = 1.0f / w_scale;
  const int tn = blockIdx.x;   // 64-wide n tile
  const int tk = blockIdx.y;   // 128-wide k tile
  const int t = threadIdx.x;
  {
    const int nn4 = t & 15;
    const int kk0 = t >> 4;    // 0..15
#pragma unroll
    for (int i = 0; i < 8; ++i) {
      const int kk = kk0 + i * 16;  // 0..127
      const float4 v =
          *(const float4*)&w[(size_t)(tk * 128 + kk) * N + tn * 64 + nn4 * 4];
      tileF[nn4 * 4 + 0][kk] = v.x;
      tileF[nn4 * 4 + 1][kk] = v.y;
      tileF[nn4 * 4 + 2][kk] = v.z;
      tileF[nn4 * 4 + 3][kk] = v.w;
    }
  }
  __syncthreads();
  {
    const int n = t & 63;
    const int c = t >> 6;      // 0..3: which 32-k chunk (wave-uniform)
    unsigned long long q[4];
#pragma unroll
    for (int cc = 0; cc < 4; ++cc) {
      const float4 u0 = *(const float4*)&tileF[n][c * 32 + cc * 8];
      const float4 u1 = *(const float4*)&tileF[n][c * 32 + cc * 8 + 4];
      uint32_t lo = __builtin_amdgcn_cvt_pk_fp8_f32(u0.x * inv, u0.y * inv, 0, false);
      lo = __builtin_amdgcn_cvt_pk_fp8_f32(u0.z * inv, u0.w * inv, lo, true);
      uint32_t hi = __builtin_amdgcn_cvt_pk_fp8_f32(u1.x * inv, u1.y * inv, 0, false);
      hi = __builtin_amdgcn_cvt_pk_fp8_f32(u1.z * inv, u1.w * inv, hi, true);
      q[cc] = (unsigned long long)lo | ((unsigned long long)hi << 32);
    }
    const int n_g = tn * 64 + n;
    const int k0g = tk * 128 + c * 32;
    const size_t slot = (size_t)(n_g >> 8) * (K >> 5) + (k0g >> 5);
    const int row = n_g & 255;
    const int mask = (row >> 2) & 3;
    // physical chunk p holds logical chunk p ^ mask
    ulonglong2 s0, s1;
    s0.x = q[0 ^ mask]; s0.y = q[1 ^ mask];
    s1.x = q[2 ^ mask]; s1.y = q[3 ^ mask];
    uint8_t* pbase = wqt + slot * 8192 + row * 32;
    *(ulonglong2*)(pbase) = s0;
    *(ulonglong2*)(pbase + 16) = s1;
  }
}

// ---------------------------------------------------------------------------
// fp8 GEMM, 256x256 tile, 8 waves (4Mx2N), 64x128 per wave (2x4 frags,
// 1.5KB LDS-read per MFMA), 32x32x64 MX MFMA, 4-slice ring, lead-2 staging,
// counted vmcnt(4) (never 0 in loop), one barrier per phase.
// ---------------------------------------------------------------------------
#define T_BM 256
#define T_BN 256
#define UNIT_SCALE 0x7F7F7F7F

__device__ __forceinline__ void gl_lds16(const uint8_t* g, uint8_t* lds) {
  __builtin_amdgcn_global_load_lds(
      (const __attribute__((address_space(1))) void*)g,
      (__attribute__((address_space(3))) void*)lds, 16, 0, 0);
}

__global__ __launch_bounds__(512, 2) void gemm_fp8_mx(
    const uint8_t* __restrict__ Aq, const uint8_t* __restrict__ BqT,
    const float* __restrict__ bias, const unsigned int* __restrict__ amax,
    float* __restrict__ C, int M, int N, int K) {
  extern __shared__ uint8_t smem[];
  uint8_t* const Ar = smem;            // 4 slices x 16384 = 64 KB
  uint8_t* const Br = smem + 65536;    // 4 slices x 16384 = 64 KB

  const int ntn = N / T_BN;
  const int bid = blockIdx.x;
  const int m0 = (bid / ntn) * T_BM;
  const int n0 = (bid % ntn) * T_BN;

  const int tid = threadIdx.x;
  const int w = tid >> 6;      // wave 0..7
  const int l = tid & 63;
  const int wr = w >> 1;       // 0..3  (M: 4 x 64)
  const int wc = w & 1;        // 0..1  (N: 2 x 128)

  const int kslots = K >> 5;

  // staging: wave w owns bytes [w*2048, +2048) of each 16KB slice (2 gl_lds).
  const int soff = w * 2048 + l * 16;
  const uint8_t* a_src = Aq + (size_t)(m0 >> 8) * kslots * 8192 + soff;
  const uint8_t* b_src = BqT + (size_t)(n0 >> 8) * kslots * 8192 + soff;

  // fragment-read offsets: lane half h = l>>5 -> slot h within the slice.
  const int h = l >> 5;
  const int rl = l & 31;
  int aoff[2][4], boff[4][4];
#pragma unroll
  for (int mt = 0; mt < 2; ++mt) {
    const int ra = wr * 64 + mt * 32 + rl;
#pragma unroll
    for (int j = 0; j < 4; ++j)
      aoff[mt][j] = h * 8192 + ra * 32 + ((j ^ ((ra >> 2) & 3)) * 8);
  }
#pragma unroll
  for (int nt = 0; nt < 4; ++nt) {
    const int rb = wc * 128 + nt * 32 + rl;
#pragma unroll
    for (int j = 0; j < 4; ++j)
      boff[nt][j] = h * 8192 + rb * 32 + ((j ^ ((rb >> 2) & 3)) * 8);
  }

  f32x16 acc[2][4];
#pragma unroll
  for (int i = 0; i < 2; ++i)
#pragma unroll
    for (int j = 0; j < 4; ++j) acc[i][j] = 0.f;

  const int NP = K >> 6;  // 64 phases (one 16 KB slice each)

  // prologue: stage slices 0,1 into ring slots 0,1 (4 loads each)
#pragma unroll
  for (int sidx = 0; sidx < 2; ++sidx) {
    gl_lds16(a_src + sidx * 16384, Ar + sidx * 16384 + soff);
    gl_lds16(a_src + sidx * 16384 + 1024, Ar + sidx * 16384 + soff + 1024);
    gl_lds16(b_src + sidx * 16384, Br + sidx * 16384 + soff);
    gl_lds16(b_src + sidx * 16384 + 1024, Br + sidx * 16384 + soff + 1024);
  }
  asm volatile("s_waitcnt vmcnt(4)" ::: "memory");  // slice 0 landed
  __builtin_amdgcn_s_barrier();

  for (int p = 0; p < NP; ++p) {
    // 1. stage slice p+2 (tail: re-stage p-2 = same bytes into its dead slot)
    const int ss = (p + 2 < NP) ? (p + 2) : (p - 2);
    const int rslot = ((p + 2) & 3) * 16384;
    gl_lds16(a_src + (size_t)ss * 16384, Ar + rslot + soff);
    gl_lds16(a_src + (size_t)ss * 16384 + 1024, Ar + rslot + soff + 1024);
    gl_lds16(b_src + (size_t)ss * 16384, Br + rslot + soff);
    gl_lds16(b_src + (size_t)ss * 16384 + 1024, Br + rslot + soff + 1024);

    // 2. fragments from ring slot p&3 (compiler-managed lgkmcnt)
    const uint8_t* Asl = Ar + (p & 3) * 16384;
    const uint8_t* Bsl = Br + (p & 3) * 16384;
    Frag32 af[2], bf[4];
#pragma unroll
    for (int mt = 0; mt < 2; ++mt)
#pragma unroll
      for (int j = 0; j < 4; ++j)
        af[mt].l[j] = *(const long*)(Asl + aoff[mt][j]);
#pragma unroll
    for (int nt = 0; nt < 4; ++nt)
#pragma unroll
      for (int j = 0; j < 4; ++j)
        bf[nt].l[j] = *(const long*)(Bsl + boff[nt][j]);

    // 3. 8 MFMAs (64x128 per wave)
    __builtin_amdgcn_s_setprio(1);
#pragma unroll
    for (int nt = 0; nt < 4; ++nt) {
      acc[0][nt] = __builtin_amdgcn_mfma_scale_f32_32x32x64_f8f6f4(
          af[0].v, bf[nt].v, acc[0][nt], 0, 0, 0, UNIT_SCALE, 0, UNIT_SCALE);
      acc[1][nt] = __builtin_amdgcn_mfma_scale_f32_32x32x64_f8f6f4(
          af[1].v, bf[nt].v, acc[1][nt], 0, 0, 0, UNIT_SCALE, 0, UNIT_SCALE);
    }
    __builtin_amdgcn_s_setprio(0);

    // 4. counted wait: slice p+1 must land; slice p+2's 4 loads stay in flight
    asm volatile("s_waitcnt vmcnt(4)" ::: "memory");
    __builtin_amdgcn_s_barrier();
  }
  asm volatile("s_waitcnt vmcnt(0)" ::: "memory");  // drain tail dummies

  // epilogue: C = acc * (x_scale*w_scale) + bias
  // 32x32 C/D layout: col = l&31, row = (r&3) + 8*(r>>2) + 4*(l>>5)
  const float x_scale = __uint_as_float(amax[1]) / 448.0f;
  const float w_scale = __uint_as_float(amax[0]) / 448.0f;
  const float s = x_scale * w_scale;
  const int colb = n0 + wc * 128 + rl;
  const int rowb = m0 + wr * 64 + 4 * h;
#pragma unroll
  for (int nt = 0; nt < 4; ++nt) {
    const int col = colb + nt * 32;
    const float bv = bias[col];
#pragma unroll
    for (int mt = 0; mt < 2; ++mt) {
#pragma unroll
      for (int r = 0; r < 16; ++r) {
        const int row = rowb + mt * 32 + (r & 3) + 8 * (r >> 2);
        C[(size_t)row * N + col] = acc[mt][nt][r] * s + bv;
      }
    }
  }
}

extern "C" void kernel_launch(void* const* d_in, const int* in_sizes, int n_in,
                              void* d_out, int out_size, void* d_ws, size_t ws_size,
                              hipStream_t stream) {
  const float* inp = (const float*)d_in[0];
  const float* weight = (const float*)d_in[1];
  const float* bias = (const float*)d_in[2];
  float* out = (float*)d_out;

  const int N = in_sizes[2];                 // 16384
  const int K = in_sizes[1] / N;             // 4096
  const int M = in_sizes[0] / K;             // 8192

  uint8_t* ws = (uint8_t*)d_ws;
  unsigned int* amax = (unsigned int*)ws;
  uint8_t* xq = ws + 256;
  uint8_t* wqt = ws + 256 + (size_t)M * K;

  hipMemsetAsync(d_ws, 0, 8, stream);  // zero the two atomic absmax slots

  absmax_kernel<<<2048, 256, 0, stream>>>((const float4*)weight,
                                          (size_t)K * N / 4, amax + 0);
  absmax_kernel<<<2048, 256, 0, stream>>>((const float4*)inp,
                                          (size_t)M * K / 4, amax + 1);

  quantize_x_kernel<<<4096, 256, 0, stream>>>((const float4*)inp, xq, amax,
                                              K, M * K / 16);
  quantize_wT_kernel<<<dim3(N / 64, K / 128), 256, 0, stream>>>(weight, wqt,
                                                                amax, N, K);

  gemm_fp8_mx<<<(M / T_BM) * (N / T_BN), 512, 131072, stream>>>(
      xq, wqt, bias, amax, out, M, N, K);
}